// Round 3
// baseline (57.079 us; speedup 1.0000x reference)
//
#include <hip/hip_runtime.h>
#include <hip/hip_cooperative_groups.h>

namespace cg = cooperative_groups;

#define NN 16
#define DD 65536
#define DD4 (DD / 4)          // 16384 float4 columns
#define BBLK 256              // blocks (one per CU); each owns 64 float4 cols
#define NITEM 136             // 16 norms + 120 dots
#define ITEMS_PER_WAVE 34
#define EPS 0.01f
#define NITERS 100
#define THRESH 0.1f

// ---------- compile-time item -> (i, j) mapping ----------
// items 0..15 : norms (i == j == item); items 16..135 : pairs i<j lexicographic
constexpr int item_i(int it) {
    if (it < NN) return it;
    int p = it - NN, i = 0;
    while (p >= 15 - i) { p -= 15 - i; ++i; }
    return i;
}
constexpr int item_j(int it) {
    if (it < NN) return it;
    int p = it - NN, i = 0;
    while (p >= 15 - i) { p -= 15 - i; ++i; }
    return i + 1 + p;
}

template <int... Ks> struct IntSeq {};
template <int N, int... S> struct MakeSeq : MakeSeq<N - 1, N - 1, S...> {};
template <int... S> struct MakeSeq<0, S...> { using type = IntSeq<S...>; };

template <int IT, int K>
__device__ __forceinline__ void acc_one(const float4 (&r)[NN], float (&acc)[ITEMS_PER_WAVE]) {
    constexpr int I = item_i(IT);
    constexpr int J = item_j(IT);
    float4 a = r[I], b = r[J];
    acc[K] = fmaf(a.w, b.w, fmaf(a.z, b.z, fmaf(a.y, b.y, fmaf(a.x, b.x, acc[K]))));
}

template <int W, int... Ks>
__device__ __forceinline__ void acc_wave(const float4 (&r)[NN], float (&acc)[ITEMS_PER_WAVE],
                                         IntSeq<Ks...>) {
    (acc_one<W * ITEMS_PER_WAVE + Ks, Ks>(r, acc), ...);
}

// ---- Fused cooperative kernel: Gram partials -> grid.sync -> Sinkhorn ----
__global__ __launch_bounds__(256) void sinkhorn_fused_kernel(
    const float* __restrict__ x, float* __restrict__ partial,
    float* __restrict__ out) {
    int tid = threadIdx.x;
    int wave = tid >> 6;
    int lane = tid & 63;

    // ================= phase 1: per-block norm/dot partials =================
    {
        int col = blockIdx.x * 64 + lane;     // float4 column index
        const float4* x4 = (const float4*)x;
        float4 r[NN];
        #pragma unroll
        for (int row = 0; row < NN; ++row) r[row] = x4[row * DD4 + col];

        float acc[ITEMS_PER_WAVE];
        #pragma unroll
        for (int k = 0; k < ITEMS_PER_WAVE; ++k) acc[k] = 0.0f;

        using Seq = MakeSeq<ITEMS_PER_WAVE>::type;
        switch (wave) {
            case 0: acc_wave<0>(r, acc, Seq{}); break;
            case 1: acc_wave<1>(r, acc, Seq{}); break;
            case 2: acc_wave<2>(r, acc, Seq{}); break;
            default: acc_wave<3>(r, acc, Seq{}); break;
        }

        #pragma unroll
        for (int k = 0; k < ITEMS_PER_WAVE; ++k) {
            float v = acc[k];
            v += __shfl_xor(v, 1, 64);
            v += __shfl_xor(v, 2, 64);
            v += __shfl_xor(v, 4, 64);
            v += __shfl_xor(v, 8, 64);
            v += __shfl_xor(v, 16, 64);
            v += __shfl_xor(v, 32, 64);
            acc[k] = v;
        }

        if (lane == 0) {
            #pragma unroll
            for (int k = 0; k < ITEMS_PER_WAVE; ++k)
                partial[(wave * ITEMS_PER_WAVE + k) * BBLK + blockIdx.x] = acc[k];
        }
    }

    // grid-wide barrier (includes device-scope memory visibility)
    cg::this_grid().sync();

    if (blockIdx.x != 0) return;

    // ================= phase 2: reduce partials, Sinkhorn, loss =============
    __shared__ float sItem[NITEM];
    __shared__ float sC[NN * 17];   // stride 17: conflict-free column reads
    __shared__ float su[NN], sv[NN], su_new[NN], sv_new[NN], sdu[NN];
    __shared__ float serr;
    __shared__ float sred[4];

    if (tid < NITEM) {
        const float4* p4 = (const float4*)(partial + tid * BBLK);
        float s0 = 0.f, s1 = 0.f, s2 = 0.f, s3 = 0.f;
        #pragma unroll
        for (int b = 0; b < BBLK / 4; ++b) {
            float4 v = p4[b];
            s0 += v.x; s1 += v.y; s2 += v.z; s3 += v.w;
        }
        sItem[tid] = (s0 + s1) + (s2 + s3);
    }
    __syncthreads();

    // C_ij = n_i + n_j - 2 d_ij  (diagonal exactly 0)
    {
        int ci = tid >> 4, cj = tid & 15;
        float c = 0.0f;
        if (ci != cj) {
            int i = ci < cj ? ci : cj;
            int j = ci < cj ? cj : ci;
            int p = i * 15 - i * (i - 1) / 2 + (j - i - 1);
            c = sItem[i] + sItem[j] - 2.0f * sItem[NN + p];
        }
        sC[ci * 17 + cj] = c;
    }
    if (tid < NN) { su[tid] = 0.0f; sv[tid] = 0.0f; }
    __syncthreads();

    const float log_mu = logf(1.0f / 16.0f);   // == log_nu

    int i_r = tid >> 4, j_r = tid & 15;   // 16-lane groups share a row
    int i_c = tid & 15, j_c = tid >> 4;   // 16-lane groups share a column

    for (int it = 0; it < NITERS; ++it) {
        // u-update: lse over rows of M(u, v)
        float e = expf((-sC[i_r * 17 + j_r] + su[i_r] + sv[j_r]) / EPS);
        e += __shfl_xor(e, 1, 64);
        e += __shfl_xor(e, 2, 64);
        e += __shfl_xor(e, 4, 64);
        e += __shfl_xor(e, 8, 64);
        if (j_r == 0) {
            float lse = logf(e + 1e-6f);
            float un = EPS * (log_mu - lse) + su[i_r];
            su_new[i_r] = un;
            sdu[i_r] = fabsf(un - su[i_r]);
        }
        __syncthreads();

        // v-update: lse over columns of M(u_new, v)
        float e2 = expf((-sC[i_c * 17 + j_c] + su_new[i_c] + sv[j_c]) / EPS);
        e2 += __shfl_xor(e2, 1, 64);
        e2 += __shfl_xor(e2, 2, 64);
        e2 += __shfl_xor(e2, 4, 64);
        e2 += __shfl_xor(e2, 8, 64);
        if (i_c == 0) {
            float lse = logf(e2 + 1e-6f);
            sv_new[j_c] = EPS * (log_mu - lse) + sv[j_c];
        }
        __syncthreads();

        if (tid == 0) {
            float err = 0.0f;
            #pragma unroll
            for (int k = 0; k < NN; ++k) err += sdu[k];
            serr = err;
        }
        if (tid < NN) {
            su[tid] = su_new[tid];
            sv[tid] = sv_new[tid];
        }
        __syncthreads();
        // Reference freezes (u,v) once err < THRESH (after this update):
        // breaking here is exactly equivalent.
        if (serr < THRESH) break;
    }

    // loss = sum(pi * C), pi = exp(M(u, v))
    float c = sC[i_r * 17 + j_r];
    float term = expf((-c + su[i_r] + sv[j_r]) / EPS) * c;
    #pragma unroll
    for (int m = 32; m >= 1; m >>= 1) term += __shfl_xor(term, m, 64);
    if ((tid & 63) == 0) sred[tid >> 6] = term;
    __syncthreads();
    if (tid == 0)
        out[0] = 10.0f * (((sred[0] + sred[1]) + sred[2]) + sred[3]);
}

extern "C" void kernel_launch(void* const* d_in, const int* in_sizes, int n_in,
                              void* d_out, int out_size, void* d_ws, size_t ws_size,
                              hipStream_t stream) {
    const float* preds_S = (const float*)d_in[0];
    // preds_T (d_in[1]) is unused by the reference.
    float* partial = (float*)d_ws;          // NITEM * BBLK floats (139 KB)
    float* out = (float*)d_out;

    void* args[] = {(void*)&preds_S, (void*)&partial, (void*)&out};
    hipLaunchCooperativeKernel((void*)sinkhorn_fused_kernel,
                               dim3(BBLK), dim3(256), args, 0, stream);
}

// Round 4
// 30.859 us; speedup vs baseline: 1.8496x; 1.8496x over previous
//
#include <hip/hip_runtime.h>

#define NN 16
#define DD 65536
#define DD4 (DD / 4)          // 16384 float4 columns
#define BBLK 256              // one block per CU; each owns 64 float4 cols
#define NITEM 136             // 16 norms + 120 dots
#define ITEMS_PER_WAVE 34
#define EPS 0.01f
#define NITERS 100
#define THRESH 0.1f

// ---------- compile-time item -> (i, j) mapping ----------
// items 0..15 : norms (i == j == item); items 16..135 : pairs i<j lexicographic
constexpr int item_i(int it) {
    if (it < NN) return it;
    int p = it - NN, i = 0;
    while (p >= 15 - i) { p -= 15 - i; ++i; }
    return i;
}
constexpr int item_j(int it) {
    if (it < NN) return it;
    int p = it - NN, i = 0;
    while (p >= 15 - i) { p -= 15 - i; ++i; }
    return i + 1 + p;
}

template <int... Ks> struct IntSeq {};
template <int N, int... S> struct MakeSeq : MakeSeq<N - 1, N - 1, S...> {};
template <int... S> struct MakeSeq<0, S...> { using type = IntSeq<S...>; };

template <int IT, int K>
__device__ __forceinline__ void acc_one(const float4 (&r)[NN], float (&acc)[ITEMS_PER_WAVE]) {
    constexpr int I = item_i(IT);
    constexpr int J = item_j(IT);
    float4 a = r[I], b = r[J];
    acc[K] = fmaf(a.w, b.w, fmaf(a.z, b.z, fmaf(a.y, b.y, fmaf(a.x, b.x, acc[K]))));
}

template <int W, int... Ks>
__device__ __forceinline__ void acc_wave(const float4 (&r)[NN], float (&acc)[ITEMS_PER_WAVE],
                                         IntSeq<Ks...>) {
    (acc_one<W * ITEMS_PER_WAVE + Ks, Ks>(r, acc), ...);
}

// ---- Single fused kernel: Gram partials -> last-block fan-in -> Sinkhorn ----
__global__ __launch_bounds__(256) void sinkhorn_onepass_kernel(
    const float* __restrict__ x, float* __restrict__ partial,
    unsigned int* __restrict__ counter, float* __restrict__ out) {
    int tid = threadIdx.x;
    int wave = tid >> 6;
    int lane = tid & 63;

    // ================= phase 1: per-block norm/dot partials =================
    {
        int col = blockIdx.x * 64 + lane;     // float4 column index
        const float4* x4 = (const float4*)x;
        float4 r[NN];
        #pragma unroll
        for (int row = 0; row < NN; ++row) r[row] = x4[row * DD4 + col];

        float acc[ITEMS_PER_WAVE];
        #pragma unroll
        for (int k = 0; k < ITEMS_PER_WAVE; ++k) acc[k] = 0.0f;

        using Seq = MakeSeq<ITEMS_PER_WAVE>::type;
        switch (wave) {
            case 0: acc_wave<0>(r, acc, Seq{}); break;
            case 1: acc_wave<1>(r, acc, Seq{}); break;
            case 2: acc_wave<2>(r, acc, Seq{}); break;
            default: acc_wave<3>(r, acc, Seq{}); break;
        }

        #pragma unroll
        for (int k = 0; k < ITEMS_PER_WAVE; ++k) {
            float v = acc[k];
            v += __shfl_xor(v, 1, 64);
            v += __shfl_xor(v, 2, 64);
            v += __shfl_xor(v, 4, 64);
            v += __shfl_xor(v, 8, 64);
            v += __shfl_xor(v, 16, 64);
            v += __shfl_xor(v, 32, 64);
            acc[k] = v;
        }

        if (lane == 0) {
            #pragma unroll
            for (int k = 0; k < ITEMS_PER_WAVE; ++k)
                partial[(wave * ITEMS_PER_WAVE + k) * BBLK + blockIdx.x] = acc[k];
        }
    }

    // ============ last-block fan-in (rocPRIM-style, no grid sync) ===========
    __shared__ unsigned int sticket;
    __syncthreads();                       // drains this block's stores (vmcnt 0)
    if (tid == 0) {
        __threadfence();                   // release: make partials device-visible
        sticket = atomicAdd(counter, 1u);  // device-scope atomic
    }
    __syncthreads();
    if (sticket != BBLK - 1) return;       // not the last block to finish
    __threadfence();                       // acquire: see all other blocks' writes

    // ================= phase 2: reduce partials, Sinkhorn, loss =============
    __shared__ float sItem[NITEM];
    __shared__ float sC[NN * 17];   // stride 17: conflict-free column reads
    __shared__ float su[NN], sv[NN], su_new[NN], sv_new[NN], sdu[NN];
    __shared__ float serr;
    __shared__ float sred[4];

    if (tid < NITEM) {
        const float4* p4 = (const float4*)(partial + tid * BBLK);
        float s0 = 0.f, s1 = 0.f, s2 = 0.f, s3 = 0.f;
        #pragma unroll
        for (int b = 0; b < BBLK / 4; ++b) {
            float4 v = p4[b];
            s0 += v.x; s1 += v.y; s2 += v.z; s3 += v.w;
        }
        sItem[tid] = (s0 + s1) + (s2 + s3);
    }
    __syncthreads();

    // C_ij = n_i + n_j - 2 d_ij  (diagonal exactly 0)
    {
        int ci = tid >> 4, cj = tid & 15;
        float c = 0.0f;
        if (ci != cj) {
            int i = ci < cj ? ci : cj;
            int j = ci < cj ? cj : ci;
            int p = i * 15 - i * (i - 1) / 2 + (j - i - 1);
            c = sItem[i] + sItem[j] - 2.0f * sItem[NN + p];
        }
        sC[ci * 17 + cj] = c;
    }
    if (tid < NN) { su[tid] = 0.0f; sv[tid] = 0.0f; }
    __syncthreads();

    const float log_mu = logf(1.0f / 16.0f);   // == log_nu

    int i_r = tid >> 4, j_r = tid & 15;   // 16-lane groups share a row
    int i_c = tid & 15, j_c = tid >> 4;   // 16-lane groups share a column

    for (int it = 0; it < NITERS; ++it) {
        // u-update: lse over rows of M(u, v)
        float e = expf((-sC[i_r * 17 + j_r] + su[i_r] + sv[j_r]) / EPS);
        e += __shfl_xor(e, 1, 64);
        e += __shfl_xor(e, 2, 64);
        e += __shfl_xor(e, 4, 64);
        e += __shfl_xor(e, 8, 64);
        if (j_r == 0) {
            float lse = logf(e + 1e-6f);
            float un = EPS * (log_mu - lse) + su[i_r];
            su_new[i_r] = un;
            sdu[i_r] = fabsf(un - su[i_r]);
        }
        __syncthreads();

        // v-update: lse over columns of M(u_new, v)
        float e2 = expf((-sC[i_c * 17 + j_c] + su_new[i_c] + sv[j_c]) / EPS);
        e2 += __shfl_xor(e2, 1, 64);
        e2 += __shfl_xor(e2, 2, 64);
        e2 += __shfl_xor(e2, 4, 64);
        e2 += __shfl_xor(e2, 8, 64);
        if (i_c == 0) {
            float lse = logf(e2 + 1e-6f);
            sv_new[j_c] = EPS * (log_mu - lse) + sv[j_c];
        }
        __syncthreads();

        if (tid == 0) {
            float err = 0.0f;
            #pragma unroll
            for (int k = 0; k < NN; ++k) err += sdu[k];
            serr = err;
        }
        if (tid < NN) {
            su[tid] = su_new[tid];
            sv[tid] = sv_new[tid];
        }
        __syncthreads();
        // Reference freezes (u,v) once err < THRESH (after this update):
        // breaking here is exactly equivalent.
        if (serr < THRESH) break;
    }

    // loss = sum(pi * C), pi = exp(M(u, v))
    float c = sC[i_r * 17 + j_r];
    float term = expf((-c + su[i_r] + sv[j_r]) / EPS) * c;
    #pragma unroll
    for (int m = 32; m >= 1; m >>= 1) term += __shfl_xor(term, m, 64);
    if ((tid & 63) == 0) sred[tid >> 6] = term;
    __syncthreads();
    if (tid == 0)
        out[0] = 10.0f * (((sred[0] + sred[1]) + sred[2]) + sred[3]);
}

extern "C" void kernel_launch(void* const* d_in, const int* in_sizes, int n_in,
                              void* d_out, int out_size, void* d_ws, size_t ws_size,
                              hipStream_t stream) {
    const float* preds_S = (const float*)d_in[0];
    // preds_T (d_in[1]) is unused by the reference.
    float* partial = (float*)d_ws;                    // NITEM*BBLK floats = 139264 B
    unsigned int* counter = (unsigned int*)((char*)d_ws + NITEM * BBLK * sizeof(float));
    float* out = (float*)d_out;

    // reset the fan-in ticket counter each call (memset node — cheap)
    hipMemsetAsync(counter, 0, sizeof(unsigned int), stream);

    hipLaunchKernelGGL(sinkhorn_onepass_kernel, dim3(BBLK), dim3(256), 0, stream,
                       preds_S, partial, counter, out);
}

// Round 5
// 18.534 us; speedup vs baseline: 3.0797x; 1.6650x over previous
//
#include <hip/hip_runtime.h>

#define NN 16
#define DD 65536
#define DD4 (DD / 4)          // 16384 float4 columns
#define BBLK 256              // kernel-1 blocks (one per CU)
#define NITEM 136             // 16 norms + 120 dots
#define ITEMS_PER_WAVE 34
#define EPS 0.01f
#define NITERS 100
#define THRESH 0.1f

// ---------- compile-time item -> (i, j) mapping ----------
// items 0..15 : norms (i == j == item); items 16..135 : pairs i<j lexicographic
constexpr int item_i(int it) {
    if (it < NN) return it;
    int p = it - NN, i = 0;
    while (p >= 15 - i) { p -= 15 - i; ++i; }
    return i;
}
constexpr int item_j(int it) {
    if (it < NN) return it;
    int p = it - NN, i = 0;
    while (p >= 15 - i) { p -= 15 - i; ++i; }
    return i + 1 + p;
}

template <int... Ks> struct IntSeq {};
template <int N, int... S> struct MakeSeq : MakeSeq<N - 1, N - 1, S...> {};
template <int... S> struct MakeSeq<0, S...> { using type = IntSeq<S...>; };

template <int IT, int K>
__device__ __forceinline__ void acc_one(const float4 (&r)[NN], float (&acc)[ITEMS_PER_WAVE]) {
    constexpr int I = item_i(IT);
    constexpr int J = item_j(IT);
    float4 a = r[I], b = r[J];
    acc[K] = fmaf(a.w, b.w, fmaf(a.z, b.z, fmaf(a.y, b.y, fmaf(a.x, b.x, acc[K]))));
}

template <int W, int... Ks>
__device__ __forceinline__ void acc_wave(const float4 (&r)[NN], float (&acc)[ITEMS_PER_WAVE],
                                         IntSeq<Ks...>) {
    (acc_one<W * ITEMS_PER_WAVE + Ks, Ks>(r, acc), ...);
}

// ---- Kernel 1: per-block partial norms & dot products ----
// 256 blocks x 256 threads; block owns 64 float4 columns (lane = column).
// Wave w accumulates items [34w, 34w+34) with static register indexing,
// 64-lane butterfly-reduces each, lane 0 writes item-major partials.
__global__ __launch_bounds__(256) void partial_kernel(
    const float* __restrict__ x, float* __restrict__ partial) {
    int wave = threadIdx.x >> 6;
    int lane = threadIdx.x & 63;
    int col = blockIdx.x * 64 + lane;     // float4 column index

    const float4* x4 = (const float4*)x;
    float4 r[NN];
    #pragma unroll
    for (int row = 0; row < NN; ++row) r[row] = x4[row * DD4 + col];

    float acc[ITEMS_PER_WAVE];
    #pragma unroll
    for (int k = 0; k < ITEMS_PER_WAVE; ++k) acc[k] = 0.0f;

    using Seq = MakeSeq<ITEMS_PER_WAVE>::type;
    switch (wave) {
        case 0: acc_wave<0>(r, acc, Seq{}); break;
        case 1: acc_wave<1>(r, acc, Seq{}); break;
        case 2: acc_wave<2>(r, acc, Seq{}); break;
        default: acc_wave<3>(r, acc, Seq{}); break;
    }

    #pragma unroll
    for (int k = 0; k < ITEMS_PER_WAVE; ++k) {
        float v = acc[k];
        v += __shfl_xor(v, 1, 64);
        v += __shfl_xor(v, 2, 64);
        v += __shfl_xor(v, 4, 64);
        v += __shfl_xor(v, 8, 64);
        v += __shfl_xor(v, 16, 64);
        v += __shfl_xor(v, 32, 64);
        acc[k] = v;
    }

    if (lane == 0) {
        #pragma unroll
        for (int k = 0; k < ITEMS_PER_WAVE; ++k)
            partial[(wave * ITEMS_PER_WAVE + k) * BBLK + blockIdx.x] = acc[k];
    }
}

// ---- Kernel 2: reduce partials, assemble C, Sinkhorn, loss ----
__global__ __launch_bounds__(256) void sinkhorn_kernel(
    const float* __restrict__ partial, float* __restrict__ out) {
    __shared__ float sItem[NITEM];
    __shared__ float sC[NN * 17];   // stride 17: conflict-free column reads
    __shared__ float su[NN], sv[NN], su_new[NN], sv_new[NN], sdu[NN];
    __shared__ float serr;
    __shared__ float sred[4];

    int tid = threadIdx.x;

    // reduce 256 block-partials per item (contiguous per item)
    if (tid < NITEM) {
        const float4* p4 = (const float4*)(partial + tid * BBLK);
        float s0 = 0.f, s1 = 0.f, s2 = 0.f, s3 = 0.f;
        #pragma unroll
        for (int b = 0; b < BBLK / 4; ++b) {
            float4 v = p4[b];
            s0 += v.x; s1 += v.y; s2 += v.z; s3 += v.w;
        }
        sItem[tid] = (s0 + s1) + (s2 + s3);
    }
    __syncthreads();

    // C_ij = n_i + n_j - 2 d_ij  (diagonal exactly 0)
    {
        int ci = tid >> 4, cj = tid & 15;
        float c = 0.0f;
        if (ci != cj) {
            int i = ci < cj ? ci : cj;
            int j = ci < cj ? cj : ci;
            int p = i * 15 - i * (i - 1) / 2 + (j - i - 1);
            c = sItem[i] + sItem[j] - 2.0f * sItem[NN + p];
        }
        sC[ci * 17 + cj] = c;
    }
    if (tid < NN) { su[tid] = 0.0f; sv[tid] = 0.0f; }
    __syncthreads();

    const float log_mu = logf(1.0f / 16.0f);   // == log_nu

    int i_r = tid >> 4, j_r = tid & 15;   // 16-lane groups share a row
    int i_c = tid & 15, j_c = tid >> 4;   // 16-lane groups share a column

    for (int it = 0; it < NITERS; ++it) {
        // u-update: lse over rows of M(u, v)
        float e = expf((-sC[i_r * 17 + j_r] + su[i_r] + sv[j_r]) / EPS);
        e += __shfl_xor(e, 1, 64);
        e += __shfl_xor(e, 2, 64);
        e += __shfl_xor(e, 4, 64);
        e += __shfl_xor(e, 8, 64);
        if (j_r == 0) {
            float lse = logf(e + 1e-6f);
            float un = EPS * (log_mu - lse) + su[i_r];
            su_new[i_r] = un;
            sdu[i_r] = fabsf(un - su[i_r]);
        }
        __syncthreads();

        // v-update: lse over columns of M(u_new, v)
        float e2 = expf((-sC[i_c * 17 + j_c] + su_new[i_c] + sv[j_c]) / EPS);
        e2 += __shfl_xor(e2, 1, 64);
        e2 += __shfl_xor(e2, 2, 64);
        e2 += __shfl_xor(e2, 4, 64);
        e2 += __shfl_xor(e2, 8, 64);
        if (i_c == 0) {
            float lse = logf(e2 + 1e-6f);
            sv_new[j_c] = EPS * (log_mu - lse) + sv[j_c];
        }
        __syncthreads();

        if (tid == 0) {
            float err = 0.0f;
            #pragma unroll
            for (int k = 0; k < NN; ++k) err += sdu[k];
            serr = err;
        }
        if (tid < NN) {
            su[tid] = su_new[tid];
            sv[tid] = sv_new[tid];
        }
        __syncthreads();
        // Reference freezes (u,v) once err < THRESH (after this update):
        // breaking here is exactly equivalent.
        if (serr < THRESH) break;
    }

    // loss = sum(pi * C), pi = exp(M(u, v))
    float c = sC[i_r * 17 + j_r];
    float term = expf((-c + su[i_r] + sv[j_r]) / EPS) * c;
    #pragma unroll
    for (int m = 32; m >= 1; m >>= 1) term += __shfl_xor(term, m, 64);
    if ((tid & 63) == 0) sred[tid >> 6] = term;
    __syncthreads();
    if (tid == 0)
        out[0] = 10.0f * (((sred[0] + sred[1]) + sred[2]) + sred[3]);
}

extern "C" void kernel_launch(void* const* d_in, const int* in_sizes, int n_in,
                              void* d_out, int out_size, void* d_ws, size_t ws_size,
                              hipStream_t stream) {
    const float* preds_S = (const float*)d_in[0];
    // preds_T (d_in[1]) is unused by the reference.
    float* partial = (float*)d_ws;          // NITEM * BBLK floats (139 KB)
    float* out = (float*)d_out;

    hipLaunchKernelGGL(partial_kernel, dim3(BBLK), dim3(256), 0, stream,
                       preds_S, partial);
    hipLaunchKernelGGL(sinkhorn_kernel, dim3(1), dim3(256), 0, stream,
                       partial, out);
}